// Round 6
// baseline (432.833 us; speedup 1.0000x reference)
//
#include <hip/hip_runtime.h>
#include <hip/hip_cooperative_groups.h>
#include <stdint.h>

namespace cg = cooperative_groups;

#define BATCH 16
#define NPTS  20000
#define TOPK  1000
#define SLICE 1250            // NPTS / 16 blocks per batch
#define NBIN  2048
#define CANDCAP 2048

__device__ __forceinline__ uint32_t key_desc(float f) {
    uint32_t u = __float_as_uint(f);
    uint32_t m = (u & 0x80000000u) ? ~u : (u | 0x80000000u);
    return ~m;                // ascending key order == descending cls
}
__device__ __forceinline__ float key_undo(uint32_t k) {
    uint32_t m = ~k;
    uint32_t u = (m & 0x80000000u) ? (m & 0x7FFFFFFFu) : ~m;
    return __uint_as_float(u);
}

// Wave-aggregated push to a global list (1 atomic per wave-op), with capacity clamp.
__device__ __forceinline__ void push64g(bool pred, uint64_t val, uint32_t* cntr,
                                        uint64_t* list, uint32_t cap, int lane) {
    uint64_t mask = __ballot(pred);
    if (mask) {
        int first = __ffsll((long long)mask) - 1;
        uint32_t base = 0;
        if (lane == first) base = atomicAdd(cntr, (uint32_t)__popcll(mask));
        base = __shfl(base, first);
        if (pred) {
            uint32_t idx = base + (uint32_t)__popcll(mask & ((1ull << lane) - 1ull));
            if (idx < cap) list[idx] = val;
        }
    }
}

__global__ __launch_bounds__(256) void nms_mega(
    const float* __restrict__ reg, const float* __restrict__ cls,
    float* __restrict__ out,
    float4* __restrict__ ws_boxes, float* __restrict__ ws_cls,
    uint32_t* __restrict__ ghist, uint64_t* __restrict__ cand,
    uint32_t* __restrict__ candcnt, uint64_t* __restrict__ sel,
    uint32_t* __restrict__ selcnt, uint32_t* __restrict__ suppT)
{
    cg::grid_group grid = cg::this_grid();

    const int b    = blockIdx.x >> 4;     // batch
    const int j    = blockIdx.x & 15;     // sub-block within batch
    const int tid  = threadIdx.x;
    const int wave = tid >> 6, lane = tid & 63;
    const float* c = cls + (size_t)b * NPTS;

    __shared__ __align__(16) uint8_t smem[21504];
    uint32_t* klds = (uint32_t*)smem;            // [0, 5120)  slice keys (1250 used)
    uint8_t*  X    = smem + 5120;                // [5120, 21504) 16384 B multi-use
    __shared__ int sh_T1, sh_r, sh_cnt1, sh_c;
    __shared__ uint64_t sh_kth;
    __shared__ uint32_t wscan[4];
    __shared__ uint32_t skept[32];

    // ================= P0: slice keys + private histogram =================
    {
        uint32_t* lhist = (uint32_t*)X;
        for (int i = tid; i < NBIN; i += 256) lhist[i] = 0;
        if (j == 0 && tid == 0) { candcnt[b] = 0; selcnt[b] = 0; }
        __syncthreads();
        #pragma unroll
        for (int q = 0; q < 5; ++q) {
            int l = tid + q * 256;
            if (l < SLICE) {
                uint32_t k = key_desc(c[SLICE * j + l]);
                klds[l] = k;
                atomicAdd(&lhist[k >> 21], 1u);
            }
        }
        __syncthreads();
        uint32_t* gh = ghist + ((size_t)b * 16 + j) * NBIN;
        for (int i = tid; i < NBIN; i += 256) gh[i] = lhist[i];
    }
    __threadfence();
    grid.sync();   // S1: all hists visible

    // ========== P1: merge 16 hists + digit-find (redundant per block) ======
    {
        const uint32_t* gh = ghist + (size_t)b * 16 * NBIN;
        uint32_t m[8], s = 0;
        #pragma unroll
        for (int u = 0; u < 8; ++u) {
            uint32_t acc = 0;
            for (int jj = 0; jj < 16; ++jj) acc += gh[jj * NBIN + 8 * tid + u];
            m[u] = acc; s += acc;
        }
        uint32_t x = s;
        #pragma unroll
        for (int d = 1; d < 64; d <<= 1) { uint32_t t2 = __shfl_up(x, d); if (lane >= d) x += t2; }
        if (lane == 63) wscan[wave] = x;
        __syncthreads();
        uint32_t wpre = 0;
        for (int w2 = 0; w2 < 4; ++w2) if (w2 < wave) wpre += wscan[w2];
        uint32_t E = wpre + x - s;
        if (999u >= E && 999u < E + s) {
            uint32_t rr = 999u - E;
            #pragma unroll
            for (int u = 0; u < 8; ++u) {
                if (rr < m[u]) { sh_T1 = 8 * tid + u; sh_r = (int)rr; sh_cnt1 = (int)m[u]; break; }
                rr -= m[u];
            }
        }
        __syncthreads();
    }
    const uint32_t T1 = (uint32_t)sh_T1;
    const int r1 = sh_r, cnt1 = sh_cnt1;

    // ================= P2: push bin-T1 candidates to global ================
    #pragma unroll
    for (int q = 0; q < 5; ++q) {
        int l = tid + q * 256;
        uint32_t k = klds[l];
        bool pred = (l < SLICE) && ((k >> 21) == T1);
        uint64_t val = ((uint64_t)k << 32) | (uint32_t)(SLICE * j + l);
        push64g(pred, val, &candcnt[b], cand + (size_t)b * CANDCAP, CANDCAP, lane);
    }
    __threadfence();
    grid.sync();   // S2: candidate list complete

    // ====== P3: kth key by counting-rank (redundant); rare exact fallback ==
    if (cnt1 <= CANDCAP) {
        uint64_t* clds = (uint64_t*)X;
        const uint64_t* gc = cand + (size_t)b * CANDCAP;
        for (int i = tid; i < cnt1; i += 256) clds[i] = gc[i];
        __syncthreads();
        for (int i = tid; i < cnt1; i += 256) {
            uint64_t e = clds[i]; int rk = 0;
            for (int m2 = 0; m2 < cnt1; ++m2) rk += (clds[m2] < e) ? 1 : 0;
            if (rk == r1) sh_kth = e;
        }
        __syncthreads();
    } else {
        // exact fallback: 53-bit binary search over full batch (block-local)
        uint64_t known = (uint64_t)T1 << 53;
        uint64_t kmask = 0xFFE0000000000000ull;
        uint32_t rr = (uint32_t)r1;
        for (int bit = 52; bit >= 0; --bit) {
            if (tid == 0) sh_c = 0;
            __syncthreads();
            uint32_t local = 0;
            for (int p = tid; p < NPTS; p += 256) {
                uint64_t k64 = ((uint64_t)key_desc(c[p]) << 32) | (uint32_t)p;
                if ((k64 & kmask) == known && !((k64 >> bit) & 1ull)) local++;
            }
            #pragma unroll
            for (int d = 1; d < 64; d <<= 1) local += __shfl_xor(local, d);
            if (lane == 0 && local) atomicAdd(&sh_c, (int)local);
            __syncthreads();
            uint32_t c0 = (uint32_t)sh_c;
            if (rr >= c0) { known |= 1ull << bit; rr -= c0; }
            kmask |= 1ull << bit;
            __syncthreads();
        }
        if (tid == 0) sh_kth = known;
        __syncthreads();
    }
    const uint64_t kthkey = sh_kth;

    // ================= P4: push selected keys (<= kth) to global ===========
    #pragma unroll
    for (int q = 0; q < 5; ++q) {
        int l = tid + q * 256;
        uint32_t k = klds[l];
        uint64_t val = ((uint64_t)k << 32) | (uint32_t)(SLICE * j + l);
        bool pred = (l < SLICE) && (val <= kthkey);
        push64g(pred, val, &selcnt[b], sel + (size_t)b * 1024, 1024, lane);
    }
    __threadfence();
    grid.sync();   // S3: selected list complete (exactly 1000)

    // ====== P5: all-pairs rank -> directly write sorted boxes/cls ==========
    {
        uint64_t* slds = (uint64_t*)X;   // 8 KB
        const uint64_t* gs = sel + (size_t)b * 1024;
        for (int i = tid; i < TOPK; i += 256) slds[i] = gs[i];
        __syncthreads();
        int i = 63 * j + tid;
        if (tid < 63 && i < TOPK) {
            uint64_t e = slds[i]; int rk = 0;
            for (int m2 = 0; m2 < TOPK; ++m2) rk += (slds[m2] < e) ? 1 : 0;
            int p = (int)(e & 0xFFFFFFFFull);
            ws_boxes[b * TOPK + rk] = ((const float4*)reg)[(size_t)b * NPTS + p];
            ws_cls[b * TOPK + rk] = key_undo((uint32_t)(e >> 32));
        }
    }
    __threadfence();
    grid.sync();   // S4: sorted boxes ready

    // ================= P6: iou suppression bitmask (transposed) ============
    {
        float4* boxes = (float4*)smem;           // [0,16000)
        float*  areas = (float*)(smem + 16000);  // [16000,20000)
        for (int i = tid; i < TOPK; i += 256) {
            float4 v = ws_boxes[b * TOPK + i];
            boxes[i] = v;
            areas[i] = (v.z - v.x) * (v.w - v.y);
        }
        __syncthreads();
        const int rbeg = j * 63;
        const int rend = (rbeg + 63 < TOPK) ? (rbeg + 63) : TOPK;
        uint32_t* t = suppT + (size_t)b * 32 * 1024;
        for (int i = rbeg + wave; i < rend; i += 4) {
            float4 a = boxes[i];
            float areaA = areas[i];
            uint64_t mine = 0;
            #pragma unroll
            for (int w = 0; w < 16; ++w) {
                int col = (w << 6) | lane;
                bool sup = false;
                if (col < TOPK) {
                    float4 bb = boxes[col];
                    float xx1 = fmaxf(a.x, bb.x);
                    float yy1 = fmaxf(a.y, bb.y);
                    float xx2 = fminf(a.z, bb.z);
                    float yy2 = fminf(a.w, bb.w);
                    float iw = fmaxf(xx2 - xx1, 0.0f);
                    float ih = fmaxf(yy2 - yy1, 0.0f);
                    float inter = iw * ih;
                    float iou = inter / (areaA + areas[col] - inter);
                    sup = (iou >= 0.5f);
                }
                uint64_t m = __ballot(sup);
                if (lane == w) mine = m;
            }
            if (lane < 16) {
                t[(2 * lane + 0) * 1024 + i] = (uint32_t)(mine & 0xFFFFFFFFull);
                t[(2 * lane + 1) * 1024 + i] = (uint32_t)(mine >> 32);
            }
        }
    }
    __threadfence();
    grid.sync();   // S5: bitmask complete

    // ================= P7: greedy sweep + output (lead block per batch) ====
    if (j == 0) {
        const uint32_t* base = suppT + (size_t)b * 32 * 1024;
        uint32_t keptw = 0;
        if (tid < 64) {
            const int myw = tid & 31;
            uint32_t remv = 0;
            uint4 dgA[8], clA[8], dgB[8], clB[8];

#define LOADG(W, DG, CL) { \
    const uint4* dp_ = (const uint4*)(base + (W) * 1024 + (W) * 32); \
    const uint4* cp_ = (const uint4*)(base + myw * 1024 + (W) * 32); \
    _Pragma("unroll") \
    for (int k_ = 0; k_ < 8; ++k_) { DG[k_] = dp_[k_]; CL[k_] = cp_[k_]; } }

#define STEP(D, C, BBIT) { \
    uint32_t live_ = (((~cur) >> (BBIT)) & 1u) & (uint32_t)((BBIT) < nb); \
    uint32_t msk_ = (uint32_t)0 - live_; \
    kmask |= (live_ << (BBIT)); \
    cur  |= (D) & msk_; \
    acc  |= (C) & msk_; }

#define PROC(W, DG, CL) { \
    const int nb = ((W) == 31) ? (TOPK - 31 * 32) : 32; \
    uint32_t cur = __shfl(remv, (W)); \
    uint32_t kmask = 0, acc = 0; \
    _Pragma("unroll") \
    for (int k_ = 0; k_ < 8; ++k_) { \
        STEP(DG[k_].x, CL[k_].x, 4 * k_ + 0); \
        STEP(DG[k_].y, CL[k_].y, 4 * k_ + 1); \
        STEP(DG[k_].z, CL[k_].z, 4 * k_ + 2); \
        STEP(DG[k_].w, CL[k_].w, 4 * k_ + 3); \
    } \
    remv |= acc; \
    if (myw == (W)) keptw = kmask; }

            LOADG(0, dgA, clA);
            #pragma unroll 1
            for (int w2 = 0; w2 < 16; ++w2) {
                const int wE = 2 * w2, wO = 2 * w2 + 1;
                LOADG(wO, dgB, clB);
                PROC(wE, dgA, clA);
                if (wO + 1 < 32) LOADG(wO + 1, dgA, clA);
                PROC(wO, dgB, clB);
            }
#undef LOADG
#undef STEP
#undef PROC
        }
        if (tid < 32) skept[tid] = keptw;
        __syncthreads();

        const float4* bx = ws_boxes + (size_t)b * TOPK;
        const float*  bc = ws_cls + (size_t)b * TOPK;
        float4* outr = (float4*)out + (size_t)b * TOPK;
        float*  outc = out + (size_t)BATCH * TOPK * 4 + (size_t)b * TOPK;
        for (int i = tid; i < TOPK; i += 256) {
            uint32_t keep = (skept[i >> 5] >> (i & 31)) & 1u;
            float4 v = bx[i];
            float cv = bc[i];
            outr[i] = keep ? v : make_float4(0.f, 0.f, 0.f, 0.f);
            outc[i] = keep ? cv : 0.0f;
        }
    }
}

extern "C" void kernel_launch(void* const* d_in, const int* in_sizes, int n_in,
                              void* d_out, int out_size, void* d_ws, size_t ws_size,
                              hipStream_t stream) {
    (void)in_sizes; (void)n_in; (void)out_size; (void)ws_size;
    const float* reg = (const float*)d_in[0];
    const float* cls = (const float*)d_in[1];
    float* out = (float*)d_out;
    char* ws = (char*)d_ws;

    float4*   ws_boxes = (float4*)ws;                         // 256000 B
    float*    ws_cls   = (float*)(ws + 256000);               // 64000 B
    uint32_t* suppT    = (uint32_t*)(ws + 320000);            // 2097152 B
    uint32_t* ghist    = (uint32_t*)(ws + 2417152);           // 2097152 B
    uint64_t* cand     = (uint64_t*)(ws + 4514304);           // 262144 B
    uint64_t* sel      = (uint64_t*)(ws + 4776448);           // 131072 B
    uint32_t* candcnt  = (uint32_t*)(ws + 4907520);           // 64 B
    uint32_t* selcnt   = (uint32_t*)(ws + 4907584);           // 64 B

    void* args[] = { (void*)&reg, (void*)&cls, (void*)&out,
                     (void*)&ws_boxes, (void*)&ws_cls, (void*)&ghist,
                     (void*)&cand, (void*)&candcnt, (void*)&sel,
                     (void*)&selcnt, (void*)&suppT };
    hipLaunchCooperativeKernel((const void*)nms_mega, dim3(256), dim3(256),
                               args, 0, stream);
}

// Round 7
// 138.948 us; speedup vs baseline: 3.1151x; 3.1151x over previous
//
#include <hip/hip_runtime.h>
#include <stdint.h>

#define BATCH 16
#define NPTS  20000
#define TOPK  1000
#define NKPT  20          // keys per thread (20*1024 >= 20000)
#define NBIN  2048
#define NCOPY 4
#define CANDCAP 2048

__device__ __forceinline__ uint32_t key_desc(float f) {
    // ascending transform, then invert -> sorting ascending by k gives cls descending
    uint32_t u = __float_as_uint(f);
    uint32_t m = (u & 0x80000000u) ? ~u : (u | 0x80000000u);
    return ~m;
}

__device__ __forceinline__ float key_undo(uint32_t k) {
    uint32_t m = ~k;
    uint32_t u = (m & 0x80000000u) ? (m & 0x7FFFFFFFu) : ~m;
    return __uint_as_float(u);
}

// Hierarchical scan over merged 2048-bin histogram (NCOPY copies); finds bin
// containing rank r, writes bin id / rank-within-bin / bin count to shared.
__device__ __forceinline__ void hist_scan_find(
    uint32_t (*wh)[NBIN], uint32_t* wsum, uint32_t* wpre,
    int* sh_T, int* sh_r, int* sh_binc,
    int tid, int wave, int lane, uint32_t r)
{
    uint32_t m0 = 0, m1 = 0;
    #pragma unroll
    for (int cpy = 0; cpy < NCOPY; ++cpy) { m0 += wh[cpy][2*tid]; m1 += wh[cpy][2*tid+1]; }
    uint32_t s = m0 + m1, x = s;
    #pragma unroll
    for (int d = 1; d < 64; d <<= 1) { uint32_t t = __shfl_up(x, d); if (lane >= d) x += t; }
    if (lane == 63) wsum[wave] = x;
    __syncthreads();
    if (wave == 0 && lane < 16) {
        uint32_t v = wsum[lane], y = v;
        #pragma unroll
        for (int d = 1; d < 16; d <<= 1) { uint32_t t = __shfl_up(y, d); if (lane >= d) y += t; }
        wpre[lane] = y - v;
    }
    __syncthreads();
    uint32_t e = wpre[wave] + (x - s);
    if (r >= e && r < e + s) {
        if (r < e + m0) { *sh_T = 2*tid;     *sh_r = (int)(r - e);      *sh_binc = (int)m0; }
        else            { *sh_T = 2*tid + 1; *sh_r = (int)(r - e - m0); *sh_binc = (int)m1; }
    }
}

// Wave-aggregated list push (1 atomic per wave-op).
__device__ __forceinline__ void push64(bool pred, uint64_t val, int* cntr,
                                       uint64_t* list, int lane) {
    uint64_t mask = __ballot(pred);
    if (mask) {
        int first = __ffsll((long long)mask) - 1;
        int base = 0;
        if (lane == first) base = atomicAdd(cntr, (int)__popcll(mask));
        base = __shfl(base, first);
        if (pred) {
            int off = (int)__popcll(mask & ((1ull << lane) - 1ull));
            list[base + off] = val;
        }
    }
}

// Wave 0 picks the r-th smallest of lst[0..n) (n<=64, keys distinct).
__device__ __forceinline__ void wave_select(const uint64_t* lst, int n, int r,
                                            uint64_t* out, int wave, int lane) {
    if (wave == 0) {
        uint64_t my = (lane < n) ? lst[lane] : ~0ull;
        int rank = 0;
        for (int i = 0; i < n; ++i) { uint64_t o = __shfl(my, i); if (o < my) rank++; }
        if (lane < n && rank == r) *out = my;
    }
}

// Exact fallback for heavy ties: block-wide bit binary search over LDS keys.
__device__ uint64_t bit_search(const uint32_t* klds, uint64_t known, uint64_t kmask,
                               int startbit, uint32_t r, int* sh_c,
                               int tid, int lane) {
    for (int bit = startbit; bit >= 0; --bit) {
        if (tid == 0) *sh_c = 0;
        __syncthreads();
        uint32_t local = 0;
        #pragma unroll
        for (int j = 0; j < NKPT; ++j) {
            int p = tid + j * 1024;
            if (p < NPTS) {
                uint64_t k64 = ((uint64_t)klds[p] << 32) | (uint32_t)p;
                if ((k64 & kmask) == known && !((k64 >> bit) & 1ull)) local++;
            }
        }
        #pragma unroll
        for (int d = 1; d < 64; d <<= 1) local += __shfl_xor(local, d);
        if (lane == 0 && local) atomicAdd(sh_c, (int)local);
        __syncthreads();
        uint32_t c0 = (uint32_t)*sh_c;
        if (r >= c0) { known |= 1ull << bit; r -= c0; }
        kmask |= 1ull << bit;
        __syncthreads();
    }
    return known;
}

// ---------------- Kernel A: exact stable top-1000 per batch ----------------
__global__ __launch_bounds__(1024) void topk_kernel(
    const float* __restrict__ reg, const float* __restrict__ cls,
    float4* __restrict__ ws_boxes, float* __restrict__ ws_cls,
    uint32_t* __restrict__ done)
{
    __shared__ uint32_t klds[NPTS];       // 78.1 KiB: all keys, LDS-cached
    __shared__ uint32_t whist[NCOPY][NBIN];
    __shared__ uint32_t wsum[16], wpre[16];
    __shared__ int      sh_T, sh_r, sh_binc, sh_cnt;
    __shared__ uint64_t sh_kthkey;
    __shared__ uint64_t cand[CANDCAP];
    __shared__ uint64_t cand2[64];
    __shared__ uint64_t sel[1024];

    const int b = blockIdx.x, tid = threadIdx.x;
    const int wave = tid >> 6, lane = tid & 63;
    const float* c = cls + (size_t)b * NPTS;

    if (tid == 0) done[b] = 0;            // reset last-block flag for kernel B

    // ---- load keys into LDS (coalesced global, stride-1 LDS) ----
    #pragma unroll
    for (int i = 0; i < NCOPY * NBIN / 1024; ++i) ((uint32_t*)whist)[tid + i * 1024] = 0;
    #pragma unroll
    for (int j = 0; j < NKPT; ++j) {
        int p = tid + j * 1024;
        if (p < NPTS) klds[p] = key_desc(c[p]);
    }
    __syncthreads();

    // ---- pass 1: 2048-bin histogram over top 11 key bits ----
    #pragma unroll
    for (int j = 0; j < NKPT; ++j) {
        int p = tid + j * 1024;
        if (p < NPTS) atomicAdd(&whist[wave >> 2][klds[p] >> 21], 1u);
    }
    __syncthreads();
    hist_scan_find(whist, wsum, wpre, &sh_T, &sh_r, &sh_binc, tid, wave, lane, TOPK - 1);
    __syncthreads();
    const int T1 = sh_T; int r = sh_r; const int cnt1 = sh_binc;
    uint64_t known = (uint64_t)(uint32_t)T1 << 53;

    if (cnt1 <= 64) {
        if (tid == 0) sh_cnt = 0;
        __syncthreads();
        #pragma unroll
        for (int j = 0; j < NKPT; ++j) {
            int p = tid + j * 1024;
            uint32_t k = (p < NPTS) ? klds[p] : 0xFFFFFFFFu;
            push64(p < NPTS && (k >> 21) == (uint32_t)T1,
                   ((uint64_t)k << 32) | (uint32_t)p, &sh_cnt, cand2, lane);
        }
        __syncthreads();
        wave_select(cand2, cnt1, r, &sh_kthkey, wave, lane);
        __syncthreads();
    } else if (cnt1 <= CANDCAP) {
        if (tid == 0) sh_cnt = 0;
        __syncthreads();
        #pragma unroll
        for (int j = 0; j < NKPT; ++j) {
            int p = tid + j * 1024;
            uint32_t k = (p < NPTS) ? klds[p] : 0xFFFFFFFFu;
            push64(p < NPTS && (k >> 21) == (uint32_t)T1,
                   ((uint64_t)k << 32) | (uint32_t)p, &sh_cnt, cand, lane);
        }
        __syncthreads();
        // ---- pass 2: 2048-bin histogram over next 11 key bits, cand only ----
        #pragma unroll
        for (int i = 0; i < NCOPY * NBIN / 1024; ++i) ((uint32_t*)whist)[tid + i * 1024] = 0;
        __syncthreads();
        for (int i = tid; i < cnt1; i += 1024)
            atomicAdd(&whist[wave >> 2][(uint32_t)((cand[i] >> 42) & 2047)], 1u);
        __syncthreads();
        hist_scan_find(whist, wsum, wpre, &sh_T, &sh_r, &sh_binc, tid, wave, lane, (uint32_t)r);
        __syncthreads();
        const int T2 = sh_T; r = sh_r; const int cnt2 = sh_binc;
        known |= (uint64_t)(uint32_t)T2 << 42;
        if (cnt2 <= 64) {
            if (tid == 0) sh_cnt = 0;
            __syncthreads();
            for (int i = tid; i < cnt1; i += 1024)
                push64(((cand[i] >> 42) & 2047) == (uint64_t)(uint32_t)T2,
                       cand[i], &sh_cnt, cand2, lane);
            __syncthreads();
            wave_select(cand2, cnt2, r, &sh_kthkey, wave, lane);
            __syncthreads();
        } else {
            uint64_t kk = bit_search(klds, known, 0xFFFFFC0000000000ull, 41,
                                     (uint32_t)r, &sh_cnt, tid, lane);
            if (tid == 0) sh_kthkey = kk;
            __syncthreads();
        }
    } else {
        uint64_t kk = bit_search(klds, known, 0xFFE0000000000000ull, 52,
                                 (uint32_t)r, &sh_cnt, tid, lane);
        if (tid == 0) sh_kthkey = kk;
        __syncthreads();
    }
    const uint64_t kthkey = sh_kthkey;

    // ---- gather exactly 1000 keys <= kthkey (wave-aggregated) ----
    if (tid == 0) sh_cnt = 0;
    sel[tid] = ~0ull;
    __syncthreads();
    #pragma unroll
    for (int j = 0; j < NKPT; ++j) {
        int p = tid + j * 1024;
        uint64_t key = (p < NPTS) ? (((uint64_t)klds[p] << 32) | (uint32_t)p) : ~0ull;
        push64(key <= kthkey, key, &sh_cnt, sel, lane);
    }
    __syncthreads();

    // ---- all-pairs rank (keys distinct) -> direct sorted scatter ----
    uint64_t e = sel[tid];
    int rk = 0;
    #pragma unroll 4
    for (int m2 = 0; m2 < 1024; ++m2) rk += (sel[m2] < e) ? 1 : 0;
    if (e != ~0ull) {
        int p = (int)(e & 0xFFFFFFFFull);
        ws_boxes[b * TOPK + rk] = ((const float4*)reg)[(size_t)b * NPTS + p];
        ws_cls[b * TOPK + rk] = key_undo((uint32_t)(e >> 32));
    }
}

// ------- Kernel B: upper-triangle iou bitmask + last-block greedy sweep -----
// suppT[b][word w][row i] = bits: columns 32w..32w+31 of supp row i.
// Lower-triangle words are written as zeros (sweep provably ignores them).
__global__ __launch_bounds__(256) void iou_sweep_kernel(
    const float4* __restrict__ ws_boxes, const float* __restrict__ ws_cls,
    uint32_t* __restrict__ suppT, uint32_t* __restrict__ done,
    float* __restrict__ out)
{
    __shared__ float4 boxes[TOPK];
    __shared__ float  areas[TOPK];
    __shared__ int    sh_last;
    __shared__ uint32_t skept[32];

    const int b     = blockIdx.y;
    const int chunk = blockIdx.x;     // 0..15, 63 rows each (1008 >= 1000)
    const int tid   = threadIdx.x;
    for (int j = tid; j < TOPK; j += 256) {
        float4 v = ws_boxes[b * TOPK + j];
        boxes[j] = v;
        areas[j] = (v.z - v.x) * (v.w - v.y);
    }
    __syncthreads();

    const int lane = tid & 63;
    const int wave = tid >> 6;        // 0..3
    const int rbeg = chunk * 63;
    const int rend = (rbeg + 63 < TOPK) ? (rbeg + 63) : TOPK;
    uint32_t* t = suppT + (size_t)b * 32 * 1024;

    for (int i = rbeg + wave; i < rend; i += 4) {
        float4 a = boxes[i];
        float areaA = areas[i];
        uint64_t mine = 0;
        for (int w = i >> 6; w < 16; ++w) {      // upper triangle only
            int col = (w << 6) | lane;
            bool sup = false;
            if (col < TOPK) {
                float4 bb = boxes[col];
                float xx1 = fmaxf(a.x, bb.x);
                float yy1 = fmaxf(a.y, bb.y);
                float xx2 = fminf(a.z, bb.z);
                float yy2 = fminf(a.w, bb.w);
                float iw = fmaxf(xx2 - xx1, 0.0f);
                float ih = fmaxf(yy2 - yy1, 0.0f);
                float inter = iw * ih;
                float iou = inter / (areaA + areas[col] - inter);
                sup = (iou >= 0.5f);
            }
            uint64_t m = __ballot(sup);
            if (lane == w) mine = m;
        }
        if (lane < 16) {
            t[(2 * lane + 0) * 1024 + i] = (uint32_t)(mine & 0xFFFFFFFFull);
            t[(2 * lane + 1) * 1024 + i] = (uint32_t)(mine >> 32);
        }
    }

    // ---- last block of this batch runs the sweep ----
    __threadfence();                   // release suppT writes (all threads)
    __syncthreads();
    if (tid == 0) sh_last = (atomicAdd(&done[b], 1u) == 15u) ? 1 : 0;
    __syncthreads();
    if (!sh_last) return;
    __threadfence();                   // acquire other blocks' suppT writes

    const uint32_t* base = suppT + (size_t)b * 32 * 1024;
    uint32_t keptw = 0;
    if (tid < 64) {
        const int myw = tid & 31;
        uint32_t remv = 0;
        uint4 dgA[8], clA[8], dgB[8], clB[8];

#define LOADG(W, DG, CL) { \
    const uint4* dp_ = (const uint4*)(base + (W) * 1024 + (W) * 32); \
    const uint4* cp_ = (const uint4*)(base + myw * 1024 + (W) * 32); \
    _Pragma("unroll") \
    for (int k_ = 0; k_ < 8; ++k_) { DG[k_] = dp_[k_]; CL[k_] = cp_[k_]; } }

#define STEP(D, C, BBIT) { \
    uint32_t live_ = (((~cur) >> (BBIT)) & 1u) & (uint32_t)((BBIT) < nb); \
    uint32_t msk_ = (uint32_t)0 - live_; \
    kmask |= (live_ << (BBIT)); \
    cur  |= (D) & msk_; \
    acc  |= (C) & msk_; }

#define PROC(W, DG, CL) { \
    const int nb = ((W) == 31) ? (TOPK - 31 * 32) : 32; \
    uint32_t cur = __shfl(remv, (W)); \
    uint32_t kmask = 0, acc = 0; \
    _Pragma("unroll") \
    for (int k_ = 0; k_ < 8; ++k_) { \
        STEP(DG[k_].x, CL[k_].x, 4 * k_ + 0); \
        STEP(DG[k_].y, CL[k_].y, 4 * k_ + 1); \
        STEP(DG[k_].z, CL[k_].z, 4 * k_ + 2); \
        STEP(DG[k_].w, CL[k_].w, 4 * k_ + 3); \
    } \
    remv |= acc; \
    if (myw == (W)) keptw = kmask; }

        LOADG(0, dgA, clA);
        #pragma unroll 1
        for (int w2 = 0; w2 < 16; ++w2) {
            const int wE = 2 * w2, wO = 2 * w2 + 1;
            LOADG(wO, dgB, clB);
            PROC(wE, dgA, clA);
            if (wO + 1 < 32) LOADG(wO + 1, dgA, clA);
            PROC(wO, dgB, clB);
        }
#undef LOADG
#undef STEP
#undef PROC
    }
    if (tid < 32) skept[tid] = keptw;
    __syncthreads();

    const float4* bx = ws_boxes + (size_t)b * TOPK;
    const float*  bc = ws_cls + (size_t)b * TOPK;
    float4* outr = (float4*)out + (size_t)b * TOPK;
    float*  outc = out + (size_t)BATCH * TOPK * 4 + (size_t)b * TOPK;
    for (int j = tid; j < TOPK; j += 256) {
        uint32_t keep = (skept[j >> 5] >> (j & 31)) & 1u;
        float4 v = bx[j];
        float cv = bc[j];
        outr[j] = keep ? v : make_float4(0.f, 0.f, 0.f, 0.f);
        outc[j] = keep ? cv : 0.0f;
    }
}

extern "C" void kernel_launch(void* const* d_in, const int* in_sizes, int n_in,
                              void* d_out, int out_size, void* d_ws, size_t ws_size,
                              hipStream_t stream) {
    (void)in_sizes; (void)n_in; (void)out_size; (void)ws_size;
    const float* reg = (const float*)d_in[0];
    const float* cls = (const float*)d_in[1];
    float* out = (float*)d_out;
    char* ws = (char*)d_ws;

    float4*   ws_boxes = (float4*)ws;                      // 16*1000*16 = 256000 B
    float*    ws_cls   = (float*)(ws + 256000);            // 64000 B
    uint32_t* suppT    = (uint32_t*)(ws + 320000);         // 16*32*1024*4 = 2097152 B
    uint32_t* done     = (uint32_t*)(ws + 2417152);        // 64 B

    topk_kernel<<<dim3(BATCH), dim3(1024), 0, stream>>>(reg, cls, ws_boxes, ws_cls, done);
    iou_sweep_kernel<<<dim3(16, BATCH), dim3(256), 0, stream>>>(ws_boxes, ws_cls, suppT, done, out);
}